// Round 10
// baseline (82.078 us; speedup 1.0000x reference)
//
#include <hip/hip_runtime.h>

// DTW via min-plus scan for MI355X (gfx950). Round 10.
// B=32, N=32, D=12, P=32, L=1024, L_OUT=32, RHO=1 => w=1.
// Per row i: D[j] = c[j] + min(a[j], D[j-1]) is a min-plus prefix scan:
//   S[j] = prefix_sum(c[i,:]),  D[j] = S[j] + prefix_min_k(a[k] - S[k-1]),
//   a[k] = min(D_prev[k-1], D_prev[k]),  S[-1] = 0.
// Lanes = columns (16 cols/lane, one wave per (b,n) problem). Rows serial.
// S[i,j] = p2[i]*(j+1) + SX2[j] - 2*sum_d p[i,d]*SXd[j], prefix sums of x.
// r10 vs r9 (kernel 43.5us, VGPR_Count=148): live state ~330 regs but the
// allocator only used 148 -> SX spilled to scratch, ~208 VMEM reloads/row
// = ~2500 stall cyc/row at 1 wave/SIMD. Single change: pin waves/EU to 1
// (amdgpu_waves_per_eu(1,1)) so the allocator gets the full ~512-reg
// unified VGPR/AGPR file (m08/m24: no spill through ~450). 1024 waves =
// exactly 1/SIMD, so occupancy cost is zero. Falsifier: VGPR_Count must
// jump to >=300; if not, next round splits the problem across 2 waves.

#define BIGF 1e30f
#define LL   1024
#define LOUT 32

using v4f = __attribute__((ext_vector_type(4))) float;

template<int CTRL>
__device__ __forceinline__ float dpp_self(float v) {   // invalid lanes keep own
    return __int_as_float(__builtin_amdgcn_update_dpp(
        __float_as_int(v), __float_as_int(v), CTRL, 0xF, 0xF, false));
}
// validated r2-r9: whole-wave shift right 1 lane; lane 0 <- 0
__device__ __forceinline__ float wshr1z(float v) {
    return __int_as_float(__builtin_amdgcn_update_dpp(
        0, __float_as_int(v), 0x138 /*wave_shr:1*/, 0xF, 0xF, false));
}
__device__ __forceinline__ float rdlane(float v, int l) {
    return __int_as_float(__builtin_amdgcn_readlane(__float_as_int(v), l));
}

// inclusive wave64 min-scan: 4 dpp row_shr hops (within 16-lane rows) +
// readlane row-combine (no row_bcast, no bpermute) — r9-validated
__device__ __forceinline__ float scan_min64_fast(float t, int lane) {
    t = fminf(t, dpp_self<0x111>(t));   // row_shr:1
    t = fminf(t, dpp_self<0x112>(t));   // row_shr:2
    t = fminf(t, dpp_self<0x114>(t));   // row_shr:4
    t = fminf(t, dpp_self<0x118>(t));   // row_shr:8
    float r0 = rdlane(t, 15), r1 = rdlane(t, 31), r2 = rdlane(t, 47);
    t = fminf(t, (lane >= 16) ? r0 : BIGF);
    t = fminf(t, (lane >= 32) ? r1 : BIGF);
    t = fminf(t, (lane >= 48) ? r2 : BIGF);
    return t;
}

// setup-only (off critical path): r8-validated shfl_up add scan
__device__ __forceinline__ float scan_add64(float t, int lane) {
#pragma unroll
    for (int d = 1; d < 64; d <<= 1) {
        float o = __shfl_up(t, (unsigned)d, 64);
        t += (lane >= d) ? o : 0.0f;
    }
    return t;
}

__global__ __launch_bounds__(64)
__attribute__((amdgpu_waves_per_eu(1, 1)))   // 1 wave/EU -> ~512-reg budget, no spill
void dtw_kernel(const float* __restrict__ x, const float* __restrict__ patts,
                float* __restrict__ out) {
    __shared__ float pT[32 * 12];   // -2*patts[n], layout [i][d]
    __shared__ float p2s[32];

    const int lane = threadIdx.x;          // lane owns cols [16*lane, 16*lane+16)
    const bool l0  = (lane == 0);
    const int blk  = blockIdx.x;           // 0..1023 = (b,n)
    const int b    = blk >> 5, n = blk & 31;
    const float* __restrict__ xb = x + b * (12 * LL);
    const float* __restrict__ pn = patts + n * (12 * 32);

    // ---- patts transpose (scaled by -2) + p2, lanes 0..31 ----
    if (lane < 32) {
        float s2 = 0.f;
#pragma unroll
        for (int d = 0; d < 12; ++d) {
            float v = pn[d * 32 + lane];
            s2 = fmaf(v, v, s2);
            pT[lane * 12 + d] = -2.0f * v;
        }
        p2s[lane] = s2;
    }

    // ---- x slice -> regs (coalesced 16B/lane) ----
    float SX[12][16];
#pragma unroll
    for (int d = 0; d < 12; ++d) {
#pragma unroll
        for (int c = 0; c < 4; ++c) {
            v4f v = *(const v4f*)(xb + d * LL + 16 * lane + 4 * c);
            SX[d][4*c+0] = v.x; SX[d][4*c+1] = v.y;
            SX[d][4*c+2] = v.z; SX[d][4*c+3] = v.w;
        }
    }
    float SX2[16];
#pragma unroll
    for (int k = 0; k < 16; ++k) {
        float a = 0.f;
#pragma unroll
        for (int d = 0; d < 12; ++d) a = fmaf(SX[d][k], SX[d][k], a);
        SX2[k] = a;
    }
    // ---- inclusive prefix sums: intra-lane serial + cross-lane shfl scan ----
#pragma unroll
    for (int d = 0; d < 12; ++d) {
#pragma unroll
        for (int k = 1; k < 16; ++k) SX[d][k] += SX[d][k-1];
        float tot = SX[d][15];
        float ex  = scan_add64(tot, lane) - tot;   // exclusive lane offset
#pragma unroll
        for (int k = 0; k < 16; ++k) SX[d][k] += ex;
    }
    {
#pragma unroll
        for (int k = 1; k < 16; ++k) SX2[k] += SX2[k-1];
        float tot = SX2[15];
        float ex  = scan_add64(tot, lane) - tot;
#pragma unroll
        for (int k = 0; k < 16; ++k) SX2[k] += ex;
    }
    float jp1[16];
#pragma unroll
    for (int k = 0; k < 16; ++k) jp1[k] = (float)(16 * lane + k + 1);

    __syncthreads();

    // ---- row 0: D = S(row 0) ----
    float pv[12], p2u;
#pragma unroll
    for (int d = 0; d < 12; ++d) pv[d] = pT[d];
    p2u = p2s[0];

    float S[16], Dp[16];
#pragma unroll
    for (int k = 0; k < 16; ++k) S[k] = fmaf(p2u, jp1[k], SX2[k]);
#pragma unroll
    for (int d = 0; d < 12; ++d)
#pragma unroll
        for (int k = 0; k < 16; ++k) S[k] = fmaf(pv[d], SX[d][k], S[k]);
#pragma unroll
    for (int k = 0; k < 16; ++k) Dp[k] = S[k];
    if (lane >= 62) {
        float* ob = out + blk * (32 * LOUT) + (lane - 62) * 16;
#pragma unroll
        for (int c = 0; c < 4; ++c) {
            v4f v = {Dp[4*c], Dp[4*c+1], Dp[4*c+2], Dp[4*c+3]};
            *(v4f*)(ob + 4 * c) = v;
        }
    }

    // ---- S for row 1 (pipelined: loop iteration i consumes S(row i)) ----
#pragma unroll
    for (int d = 0; d < 12; ++d) pv[d] = pT[12 + d];
    p2u = p2s[1];
#pragma unroll
    for (int k = 0; k < 16; ++k) S[k] = fmaf(p2u, jp1[k], SX2[k]);
#pragma unroll
    for (int d = 0; d < 12; ++d)
#pragma unroll
        for (int k = 0; k < 16; ++k) S[k] = fmaf(pv[d], SX[d][k], S[k]);

    // ---- rows 1..31 ----
#pragma unroll 1
    for (int i = 1; i < 32; ++i) {
        const int ip = (i + 1 < 32) ? i + 1 : 31;
        float pvn[12];
#pragma unroll
        for (int d = 0; d < 12; ++d) pvn[d] = pT[ip * 12 + d];
        float p2n = p2s[ip];

        // boundary values from the left neighbor (validated primitive)
        float dsh = wshr1z(Dp[15]); dsh = l0 ? BIGF : dsh;  // D_prev[j-1] at k=0
        float se  = wshr1z(S[15]);                          // S[j-1] at k=0 (lane0->0)

        // z[k] = a[k] - S[k-1]; intra-lane inclusive min-scan m
        float m[16];
        m[0] = fminf(dsh, Dp[0]) - se;
#pragma unroll
        for (int k = 1; k < 16; ++k)
            m[k] = fminf(m[k-1], fminf(Dp[k-1], Dp[k]) - S[k-1]);

        // cross-lane inclusive min-scan of lane totals (fast DPP+readlane)
        float t = scan_min64_fast(m[15], lane);

        // ---- next row's S: independent of t -> fills the scan latency ----
        float Sn[16];
#pragma unroll
        for (int k = 0; k < 16; ++k) Sn[k] = fmaf(p2n, jp1[k], SX2[k]);
#pragma unroll
        for (int d = 0; d < 12; ++d)
#pragma unroll
            for (int k = 0; k < 16; ++k) Sn[k] = fmaf(pvn[d], SX[d][k], Sn[k]);

        float te = wshr1z(t); te = l0 ? BIGF : te;          // exclusive
#pragma unroll
        for (int k = 0; k < 16; ++k) Dp[k] = S[k] + fminf(te, m[k]);

        if (lane >= 62) {
            float* ob = out + blk * (32 * LOUT) + (lane - 62) * 16;
#pragma unroll
            for (int c = 0; c < 4; ++c) {
                v4f v = {Dp[4*c], Dp[4*c+1], Dp[4*c+2], Dp[4*c+3]};
                *(v4f*)(ob + i * 32 + 4 * c) = v;
            }
        }
#pragma unroll
        for (int k = 0; k < 16; ++k) S[k] = Sn[k];
    }
}

extern "C" void kernel_launch(void* const* d_in, const int* in_sizes, int n_in,
                              void* d_out, int out_size, void* d_ws, size_t ws_size,
                              hipStream_t stream) {
    const float* x     = (const float*)d_in[0];   // [32,12,1024] f32
    const float* patts = (const float*)d_in[1];   // [32,12,32]   f32
    float* out         = (float*)d_out;           // [32,32,32,32] f32
    dtw_kernel<<<dim3(1024), dim3(64), 0, stream>>>(x, patts, out);
}